// Round 1
// baseline (3627.087 us; speedup 1.0000x reference)
//
#include <hip/hip_runtime.h>

typedef unsigned short u16;
typedef __bf16 bf16x8 __attribute__((ext_vector_type(8)));
typedef float f32x4 __attribute__((ext_vector_type(4)));

#define DEVI __device__ __forceinline__

DEVI u16 f2b(float f) {
  union { float f; unsigned u; } c; c.f = f;
  unsigned r = c.u + 0x7FFFu + ((c.u >> 16) & 1u);
  return (u16)(r >> 16);
}

DEVI float sigm(float x) { return 1.f / (1.f + __expf(-x)); }
DEVI float tanhfast(float x) {
  x = fminf(fmaxf(x, -15.f), 15.f);
  float e = __expf(2.f * x);
  return (e - 1.f) / (e + 1.f);
}

DEVI void async16(const void* g, void* l) {
  __builtin_amdgcn_global_load_lds((const __attribute__((address_space(1))) void*)g,
                                   (__attribute__((address_space(3))) void*)l, 16, 0, 0);
}

// ---------------- cast / pad fp32 -> bf16 ----------------
__global__ __launch_bounds__(256) void k_castpad(const float* __restrict__ src, u16* __restrict__ dst,
                                                 int srows, int scols, int drows, int dcols) {
  size_t n = (size_t)drows * dcols;
  for (size_t i = blockIdx.x * 256 + threadIdx.x; i < n; i += (size_t)gridDim.x * 256) {
    int r = (int)(i / dcols), c = (int)(i % dcols);
    float v = (r < srows && c < scols) ? src[(size_t)r * scols + c] : 0.f;
    dst[i] = f2b(v);
  }
}

// ---------------- embedding + time concat -> x0 bf16 [8192][288] ----------------
__global__ __launch_bounds__(256) void k_embed(const int* __restrict__ loc, const float* __restrict__ times,
                                               const float* __restrict__ emb, u16* __restrict__ x0) {
  int m = blockIdx.x * 4 + (threadIdx.x >> 6);  // m = t*32 + b
  int s = threadIdx.x & 63;
  int b = m & 31, t = m >> 5;
  int li = loc[b * 256 + t];
  const float4* er = (const float4*)(emb + (size_t)li * 256);
  u16* xr = x0 + (size_t)m * 288;
  float4 v = er[s];
  ushort4 u;
  u.x = f2b(v.x); u.y = f2b(v.y); u.z = f2b(v.z); u.w = f2b(v.w);
  *(ushort4*)(xr + s * 4) = u;
  if (s == 0) xr[256] = f2b(times[b * 256 + t]);
  else if (s <= 31) xr[256 + s] = 0;
}

// ---------------- init h0 (bf16) from traj_emb[labels].reshape(2,32,512) ----------------
__global__ __launch_bounds__(256) void k_hinit(const float* __restrict__ traj, const int* __restrict__ labels,
                                               u16* __restrict__ hbuf, int layer) {
  int idx = blockIdx.x * 256 + threadIdx.x;
  if (idx < 16384) {
    int fidx = layer * 16384 + idx;
    hbuf[idx] = f2b(traj[(size_t)labels[fidx >> 10] * 1024 + (fidx & 1023)]);
  }
}

// ---------------- bf16 MFMA GEMM: C[M,N] = A[M,K] * Bw[N,K]^T (+bias) ----------------
// MODE 0: C fp32 ldc=N, bias added.   MODE 1 (FC): row remap, col<10000 -> logits, col==10000 -> sigmoid time
template <int MODE>
__global__ __launch_bounds__(256) void k_gemm(const u16* __restrict__ A, const u16* __restrict__ Bw,
                                              const float* __restrict__ bias, float* __restrict__ C,
                                              int N, int K, float* __restrict__ tptr) {
  __shared__ __align__(16) u16 As[128 * 32];
  __shared__ __align__(16) u16 Bs[128 * 32];
  const int tid = threadIdx.x;
  const int lane = tid & 63, wid = tid >> 6;
  const int tn = blockIdx.x, tm = blockIdx.y;
  const int wm = wid >> 1, wn = wid & 1;

  f32x4 acc[4][4] = {};

  const int r0 = tid >> 2;            // (tid*16)/64
  const int cb0 = (tid * 16) & 63;    // byte col within 64B row

  for (int k0 = 0; k0 < K; k0 += 32) {
    __syncthreads();
#pragma unroll
    for (int p = 0; p < 2; ++p) {
      int row = r0 + p * 64;
      const u16* ga = A + (size_t)(tm * 128 + row) * K + k0 + (cb0 >> 1);
      async16(ga, (void*)(As + wid * 512 + p * 2048));
      const u16* gb = Bw + (size_t)(tn * 128 + row) * K + k0 + (cb0 >> 1);
      async16(gb, (void*)(Bs + wid * 512 + p * 2048));
    }
    asm volatile("s_waitcnt vmcnt(0)" ::: "memory");
    __syncthreads();
    bf16x8 af[4], bf[4];
#pragma unroll
    for (int i = 0; i < 4; ++i) {
      af[i] = *reinterpret_cast<const bf16x8*>(As + (wm * 64 + i * 16 + (lane & 15)) * 32 + ((lane >> 4) * 8));
      bf[i] = *reinterpret_cast<const bf16x8*>(Bs + (wn * 64 + i * 16 + (lane & 15)) * 32 + ((lane >> 4) * 8));
    }
#pragma unroll
    for (int i = 0; i < 4; ++i)
#pragma unroll
      for (int j = 0; j < 4; ++j)
        acc[i][j] = __builtin_amdgcn_mfma_f32_16x16x32_bf16(af[i], bf[j], acc[i][j], 0, 0, 0);
  }

  const int row0 = tm * 128 + wm * 64;
  const int col0 = tn * 128 + wn * 64;
#pragma unroll
  for (int i = 0; i < 4; ++i)
#pragma unroll
    for (int j = 0; j < 4; ++j)
#pragma unroll
      for (int r = 0; r < 4; ++r) {
        int row = row0 + i * 16 + ((lane >> 4) * 4) + r;
        int col = col0 + j * 16 + (lane & 15);
        float v = acc[i][j][r];
        if (MODE == 0) {
          C[(size_t)row * N + col] = v + bias[col];
        } else {
          int orow = ((row & 31) << 8) + (row >> 5);  // b*256 + t
          if (col < 10000) C[(size_t)orow * 10000 + col] = v + bias[col];
          else if (col == 10000) tptr[orow] = sigm(v + bias[col]);
        }
      }
}

// ---------------- persistent GRU scan: 32 blocks, each owns 16 hidden cols ----------------
#define NBLK 32
template <int LAYER>
__global__ __launch_bounds__(512) void k_scan(const float* __restrict__ xg, const u16* __restrict__ whh,
                                              const float* __restrict__ bhh, const float* __restrict__ traj,
                                              const int* __restrict__ labels, u16* __restrict__ hbuf,
                                              u16* __restrict__ hseq, int* __restrict__ flags) {
  const int tid = threadIdx.x;
  const int blk = blockIdx.x;
  const int lane = tid & 63, wid = tid >> 6;
  __shared__ float smD[2][3][16][16];

  const int eb = tid >> 4, ejj = tid & 15;   // epilogue element: batch eb, col ejj
  const int jg = (blk << 4) + ejj;           // global hidden col

  int fidx = LAYER * 16384 + eb * 512 + jg;
  float h_own = traj[(size_t)labels[fidx >> 10] * 1024 + (fidx & 1023)];

  const float bh_r = bhh[jg], bh_z = bhh[512 + jg], bh_n = bhh[1024 + jg];

  const int mt = wid / 3, nt = wid % 3;      // valid for wid<6 (2 M-tiles x 3 gates)
  bf16x8 bfrag[16];
  if (wid < 6) {
    const u16* wrow = whh + (size_t)(nt * 512 + (blk << 4) + (lane & 15)) * 512 + ((lane >> 4) * 8);
#pragma unroll
    for (int ks = 0; ks < 16; ++ks)
      bfrag[ks] = *reinterpret_cast<const bf16x8*>(wrow + ks * 32);
  }

  const float* xgp = xg + (size_t)eb * 1536 + jg;
  float xr = xgp[0], xz = xgp[512], xn = xgp[1024];

  for (int t = 0; t < 256; ++t) {
    if (wid < 6) {
      const u16* arow = hbuf + ((t & 1) << 14) + ((mt * 16 + (lane & 15)) << 9) + ((lane >> 4) * 8);
      bf16x8 af[16];
#pragma unroll
      for (int ks = 0; ks < 16; ++ks)
        af[ks] = *reinterpret_cast<const bf16x8*>(arow + ks * 32);
      f32x4 a0 = {0.f, 0.f, 0.f, 0.f}, a1 = {0.f, 0.f, 0.f, 0.f};
#pragma unroll
      for (int ks = 0; ks < 8; ++ks) {
        a0 = __builtin_amdgcn_mfma_f32_16x16x32_bf16(af[2 * ks], bfrag[2 * ks], a0, 0, 0, 0);
        a1 = __builtin_amdgcn_mfma_f32_16x16x32_bf16(af[2 * ks + 1], bfrag[2 * ks + 1], a1, 0, 0, 0);
      }
      const int col = lane & 15, rb = (lane >> 4) << 2;
#pragma unroll
      for (int r = 0; r < 4; ++r)
        smD[mt][nt][rb + r][col] = a0[r] + a1[r];
    }
    __syncthreads();
    float Dr = smD[eb >> 4][0][eb & 15][ejj] + bh_r;
    float Dz = smD[eb >> 4][1][eb & 15][ejj] + bh_z;
    float Dn = smD[eb >> 4][2][eb & 15][ejj] + bh_n;
    float r = sigm(xr + Dr);
    float z = sigm(xz + Dz);
    float n = tanhfast(xn + r * Dn);
    h_own = (1.f - z) * n + z * h_own;
    u16 hb = f2b(h_own);
    hbuf[(((t + 1) & 1) << 14) + (eb << 9) + jg] = hb;
    hseq[((size_t)(t * 32 + eb) << 9) + jg] = (LAYER == 1) ? f2b(fmaxf(h_own, 0.f)) : hb;
    // prefetch next step's x-gates (constant data; survives the fence in regs)
    float nxr = 0.f, nxz = 0.f, nxn = 0.f;
    if (t < 255) {
      const float* q = xgp + (size_t)(t + 1) * 49152;
      nxr = q[0]; nxz = q[512]; nxn = q[1024];
    }
    // device-scope grid barrier
    __syncthreads();
    if (tid == 0) {
      __hip_atomic_fetch_add(&flags[t], 1, __ATOMIC_RELEASE, __HIP_MEMORY_SCOPE_AGENT);
      while (__hip_atomic_load(&flags[t], __ATOMIC_RELAXED, __HIP_MEMORY_SCOPE_AGENT) < NBLK) {}
      __builtin_amdgcn_fence(__ATOMIC_ACQUIRE, "agent");
    }
    __syncthreads();
    xr = nxr; xz = nxz; xn = nxn;
  }
}

// ---------------- in-place log_softmax over rows of 10000 ----------------
__global__ __launch_bounds__(256) void k_logsoftmax(float* __restrict__ out) {
  const int row = blockIdx.x, tid = threadIdx.x;
  float* p = out + (size_t)row * 10000;
  const int n_own = (tid < 16) ? 40 : 39;  // 256*39 + 16 = 10000
  float v[40];
  float mx = -3.4e38f;
#pragma unroll
  for (int i = 0; i < 40; ++i)
    if (i < n_own) { v[i] = p[i * 256 + tid]; mx = fmaxf(mx, v[i]); }
  for (int o = 32; o; o >>= 1) mx = fmaxf(mx, __shfl_xor(mx, o));
  __shared__ float sm[4], ss[4];
  if ((tid & 63) == 0) sm[tid >> 6] = mx;
  __syncthreads();
  mx = fmaxf(fmaxf(sm[0], sm[1]), fmaxf(sm[2], sm[3]));
  float s = 0.f;
#pragma unroll
  for (int i = 0; i < 40; ++i)
    if (i < n_own) s += __expf(v[i] - mx);
  for (int o = 32; o; o >>= 1) s += __shfl_xor(s, o);
  if ((tid & 63) == 0) ss[tid >> 6] = s;
  __syncthreads();
  s = ss[0] + ss[1] + ss[2] + ss[3];
  float lse = mx + __logf(s);
#pragma unroll
  for (int i = 0; i < 40; ++i)
    if (i < n_own) p[i * 256 + tid] = v[i] - lse;
}

extern "C" void kernel_launch(void* const* d_in, const int* in_sizes, int n_in,
                              void* d_out, int out_size, void* d_ws, size_t ws_size,
                              hipStream_t stream) {
  (void)in_sizes; (void)n_in; (void)out_size;
  const int*   loc    = (const int*)  d_in[0];
  const float* times  = (const float*)d_in[1];
  const int*   labels = (const int*)  d_in[2];
  const float* emb    = (const float*)d_in[3];
  const float* traj   = (const float*)d_in[4];
  const float* w_ih0  = (const float*)d_in[5];
  const float* w_hh0  = (const float*)d_in[6];
  const float* b_ih0  = (const float*)d_in[7];
  const float* b_hh0  = (const float*)d_in[8];
  const float* w_ih1  = (const float*)d_in[9];
  const float* w_hh1  = (const float*)d_in[10];
  const float* b_ih1  = (const float*)d_in[11];
  const float* b_hh1  = (const float*)d_in[12];
  const float* fc_w   = (const float*)d_in[13];
  const float* fc_b   = (const float*)d_in[14];

  if (ws_size < 37521408) return;  // need ~35.8 MB scratch

  char* ws = (char*)d_ws;
  size_t off = 0;
  auto alloc = [&](size_t b) { size_t r = off; off += (b + 255) & ~(size_t)255; return r; };
  int* flags   = (int*)(ws + alloc(2 * 256 * 4));
  u16* hbuf    = (u16*)(ws + alloc(2 * 32 * 512 * 2));
  u16* x0      = (u16*)(ws + alloc((size_t)8192 * 288 * 2));
  u16* wih0b   = (u16*)(ws + alloc((size_t)1536 * 288 * 2));
  u16* whh0b   = (u16*)(ws + alloc((size_t)1536 * 512 * 2));
  u16* wih1b   = (u16*)(ws + alloc((size_t)1536 * 512 * 2));
  u16* whh1b   = (u16*)(ws + alloc((size_t)1536 * 512 * 2));
  u16* fcwb    = (u16*)(ws + alloc((size_t)10112 * 512 * 2));
  u16* h0seq   = (u16*)(ws + alloc((size_t)8192 * 512 * 2));
  u16* h1seq   = (u16*)(ws + alloc((size_t)8192 * 512 * 2));

  float* outp = (float*)d_out;
  float* xg0  = outp;                  // [8192][1536] scratch in d_out (dead until FC)
  float* xg1  = outp + 12582912;       // [8192][1536]
  float* tptr = outp + 81920000;       // time [8192]

  hipMemsetAsync(flags, 0, 2 * 256 * 4, stream);
  k_castpad<<<1024, 256, 0, stream>>>(w_ih0, wih0b, 1536, 257, 1536, 288);
  k_castpad<<<1024, 256, 0, stream>>>(w_hh0, whh0b, 1536, 512, 1536, 512);
  k_castpad<<<1024, 256, 0, stream>>>(w_ih1, wih1b, 1536, 512, 1536, 512);
  k_castpad<<<1024, 256, 0, stream>>>(w_hh1, whh1b, 1536, 512, 1536, 512);
  k_castpad<<<1024, 256, 0, stream>>>(fc_w, fcwb, 10001, 512, 10112, 512);
  k_embed<<<2048, 256, 0, stream>>>(loc, times, emb, x0);
  k_gemm<0><<<dim3(12, 64), 256, 0, stream>>>(x0, wih0b, b_ih0, xg0, 1536, 288, nullptr);
  k_hinit<<<64, 256, 0, stream>>>(traj, labels, hbuf, 0);
  k_scan<0><<<NBLK, 512, 0, stream>>>(xg0, whh0b, b_hh0, traj, labels, hbuf, h0seq, flags);
  k_gemm<0><<<dim3(12, 64), 256, 0, stream>>>(h0seq, wih1b, b_ih1, xg1, 1536, 512, nullptr);
  k_hinit<<<64, 256, 0, stream>>>(traj, labels, hbuf, 1);
  k_scan<1><<<NBLK, 512, 0, stream>>>(xg1, whh1b, b_hh1, traj, labels, hbuf, h1seq, flags + 256);
  k_gemm<1><<<dim3(79, 64), 256, 0, stream>>>(h1seq, fcwb, fc_b, outp, 10112, 512, tptr);
  k_logsoftmax<<<8192, 256, 0, stream>>>(outp);
}

// Round 2
// 1840.700 us; speedup vs baseline: 1.9705x; 1.9705x over previous
//
#include <hip/hip_runtime.h>

typedef unsigned short u16;
typedef __bf16 bf16x8 __attribute__((ext_vector_type(8)));
typedef float f32x4 __attribute__((ext_vector_type(4)));

#define DEVI __device__ __forceinline__

DEVI u16 f2b(float f) {
  union { float f; unsigned u; } c; c.f = f;
  unsigned r = c.u + 0x7FFFu + ((c.u >> 16) & 1u);
  return (u16)(r >> 16);
}

DEVI float sigm(float x) { return 1.f / (1.f + __expf(-x)); }
DEVI float tanhfast(float x) {
  x = fminf(fmaxf(x, -15.f), 15.f);
  float e = __expf(2.f * x);
  return (e - 1.f) / (e + 1.f);
}

DEVI void async16(const void* g, void* l) {
  __builtin_amdgcn_global_load_lds((const __attribute__((address_space(1))) void*)g,
                                   (__attribute__((address_space(3))) void*)l, 16, 0, 0);
}

// Coherence-point (LLC) bypass 16B load: sc0 sc1 skips the non-coherent L1/L2.
// NOTE: no waitcnt inside — caller must s_waitcnt vmcnt(0) + sched_barrier(0)
// before consuming (guide rule 18).
DEVI f32x4 ld16cc(const u16* p) {
  f32x4 r;
  asm volatile("global_load_dwordx4 %0, %1, off sc0 sc1" : "=v"(r) : "v"(p) : "memory");
  return r;
}

// ---------------- cast / pad fp32 -> bf16 ----------------
__global__ __launch_bounds__(256) void k_castpad(const float* __restrict__ src, u16* __restrict__ dst,
                                                 int srows, int scols, int drows, int dcols) {
  size_t n = (size_t)drows * dcols;
  for (size_t i = blockIdx.x * 256 + threadIdx.x; i < n; i += (size_t)gridDim.x * 256) {
    int r = (int)(i / dcols), c = (int)(i % dcols);
    float v = (r < srows && c < scols) ? src[(size_t)r * scols + c] : 0.f;
    dst[i] = f2b(v);
  }
}

// ---------------- embedding + time concat -> x0 bf16 [8192][288] ----------------
__global__ __launch_bounds__(256) void k_embed(const int* __restrict__ loc, const float* __restrict__ times,
                                               const float* __restrict__ emb, u16* __restrict__ x0) {
  int m = blockIdx.x * 4 + (threadIdx.x >> 6);  // m = t*32 + b
  int s = threadIdx.x & 63;
  int b = m & 31, t = m >> 5;
  int li = loc[b * 256 + t];
  const float4* er = (const float4*)(emb + (size_t)li * 256);
  u16* xr = x0 + (size_t)m * 288;
  float4 v = er[s];
  ushort4 u;
  u.x = f2b(v.x); u.y = f2b(v.y); u.z = f2b(v.z); u.w = f2b(v.w);
  *(ushort4*)(xr + s * 4) = u;
  if (s == 0) xr[256] = f2b(times[b * 256 + t]);
  else if (s <= 31) xr[256 + s] = 0;
}

// ---------------- init h seed (bf16) from traj_emb[labels] ----------------
__global__ __launch_bounds__(256) void k_hinit(const float* __restrict__ traj, const int* __restrict__ labels,
                                               u16* __restrict__ dst, int layer) {
  int idx = blockIdx.x * 256 + threadIdx.x;
  if (idx < 16384) {
    int fidx = layer * 16384 + idx;
    dst[idx] = f2b(traj[(size_t)labels[fidx >> 10] * 1024 + (fidx & 1023)]);
  }
}

// ---------------- bf16 MFMA GEMM: C[M,N] = A[M,K] * Bw[N,K]^T (+bias) ----------------
template <int MODE>
__global__ __launch_bounds__(256) void k_gemm(const u16* __restrict__ A, const u16* __restrict__ Bw,
                                              const float* __restrict__ bias, float* __restrict__ C,
                                              int N, int K, float* __restrict__ tptr) {
  __shared__ __align__(16) u16 As[128 * 32];
  __shared__ __align__(16) u16 Bs[128 * 32];
  const int tid = threadIdx.x;
  const int lane = tid & 63, wid = tid >> 6;
  const int tn = blockIdx.x, tm = blockIdx.y;
  const int wm = wid >> 1, wn = wid & 1;

  f32x4 acc[4][4] = {};

  const int r0 = tid >> 2;
  const int cb0 = (tid * 16) & 63;

  for (int k0 = 0; k0 < K; k0 += 32) {
    __syncthreads();
#pragma unroll
    for (int p = 0; p < 2; ++p) {
      int row = r0 + p * 64;
      const u16* ga = A + (size_t)(tm * 128 + row) * K + k0 + (cb0 >> 1);
      async16(ga, (void*)(As + wid * 512 + p * 2048));
      const u16* gb = Bw + (size_t)(tn * 128 + row) * K + k0 + (cb0 >> 1);
      async16(gb, (void*)(Bs + wid * 512 + p * 2048));
    }
    asm volatile("s_waitcnt vmcnt(0)" ::: "memory");
    __syncthreads();
    bf16x8 af[4], bf[4];
#pragma unroll
    for (int i = 0; i < 4; ++i) {
      af[i] = *reinterpret_cast<const bf16x8*>(As + (wm * 64 + i * 16 + (lane & 15)) * 32 + ((lane >> 4) * 8));
      bf[i] = *reinterpret_cast<const bf16x8*>(Bs + (wn * 64 + i * 16 + (lane & 15)) * 32 + ((lane >> 4) * 8));
    }
#pragma unroll
    for (int i = 0; i < 4; ++i)
#pragma unroll
      for (int j = 0; j < 4; ++j)
        acc[i][j] = __builtin_amdgcn_mfma_f32_16x16x32_bf16(af[i], bf[j], acc[i][j], 0, 0, 0);
  }

  const int row0 = tm * 128 + wm * 64;
  const int col0 = tn * 128 + wn * 64;
#pragma unroll
  for (int i = 0; i < 4; ++i)
#pragma unroll
    for (int j = 0; j < 4; ++j)
#pragma unroll
      for (int r = 0; r < 4; ++r) {
        int row = row0 + i * 16 + ((lane >> 4) * 4) + r;
        int col = col0 + j * 16 + (lane & 15);
        float v = acc[i][j][r];
        if (MODE == 0) {
          C[(size_t)row * N + col] = v + bias[col];
        } else {
          int orow = ((row & 31) << 8) + (row >> 5);  // b*256 + t
          if (col < 10000) C[(size_t)orow * 10000 + col] = v + bias[col];
          else if (col == 10000) tptr[orow] = sigm(v + bias[col]);
        }
      }
}

// ---------------- fused persistent 2-layer GRU scan ----------------
// 64 blocks x 512 thr. Blocks 0-31 ("merged"): own 16 h0-cols; per interval s
// load h0(s-1) fragments ONCE, MFMA vs w_hh0 (-> h0(s)) AND vs w_ih1
// (-> X1(s-1), layer-1 x-gates, published fp32). Blocks 32-63 ("l1h"): own 16
// h1-cols; compute h1(s-2) from X1(s-2) + w_hh1 @ h1(s-3); write relu to h1seq.
// All cross-block traffic is LLC-bypass (sc0 sc1); barrier = relaxed adds on
// 8 spread sub-flags, NO wbl2/inv fences anywhere.
#define NB 64

__global__ __launch_bounds__(512, 2) void k_scan2(
    const float* __restrict__ xg0,
    const u16* __restrict__ whh0, const float* __restrict__ bhh0,
    const u16* __restrict__ wih1, const float* __restrict__ bih1,
    const u16* __restrict__ whh1, const float* __restrict__ bhh1,
    const float* __restrict__ traj, const int* __restrict__ labels,
    u16* __restrict__ h0x, u16* __restrict__ h1x, float* __restrict__ x1x,
    u16* __restrict__ h1seq, int* __restrict__ flags)
{
  const int tid = threadIdx.x, bid = blockIdx.x;
  const int role = bid >> 5, blk = bid & 31;  // 0: merged L0+L1X, 1: L1H
  const int lane = tid & 63, wid = tid >> 6;
  __shared__ float smD[2][3][16][16];

  const int eb = tid >> 4, ejj = tid & 15;
  const int jg = (blk << 4) + ejj;

  // epilogue state
  const float* bhh = (role == 0) ? bhh0 : bhh1;
  int fidx = (role == 1 ? 16384 : 0) + eb * 512 + jg;
  float h_own = traj[(size_t)labels[fidx >> 10] * 1024 + (fidx & 1023)];
  const float bh_r = bhh[jg], bh_z = bhh[512 + jg], bh_n = bhh[1024 + jg];

  const int mt = (wid < 6) ? wid / 3 : 0, nt = (wid < 6) ? wid % 3 : 0;
  bf16x8 bfragH[16];  // w_hh0 (merged) or w_hh1 (l1h)
  bf16x8 bfragX[16];  // w_ih1 (merged only)
  float bX = 0.f;
  if (wid < 6) {
    const u16* wh = (role == 0) ? whh0 : whh1;
    const u16* wrow = wh + (size_t)(nt * 512 + (blk << 4) + (lane & 15)) * 512 + ((lane >> 4) * 8);
#pragma unroll
    for (int ks = 0; ks < 16; ++ks)
      bfragH[ks] = *reinterpret_cast<const bf16x8*>(wrow + ks * 32);
    if (role == 0) {
      const u16* xrow = wih1 + (size_t)(nt * 512 + (blk << 4) + (lane & 15)) * 512 + ((lane >> 4) * 8);
#pragma unroll
      for (int ks = 0; ks < 16; ++ks)
        bfragX[ks] = *reinterpret_cast<const bf16x8*>(xrow + ks * 32);
      bX = bih1[nt * 512 + (blk << 4) + (lane & 15)];
    }
  }

  const u16* hsrc = (role == 0) ? h0x : h1x;
  u16* hdst = (role == 0) ? h0x : h1x;

  for (int s = 0; s < 258; ++s) {
    const int wp = s & 1, rp = (s + 1) & 1;
    if (role == 0) {
      if (s <= 256) {
        float gxr = 0.f, gxz = 0.f, gxn = 0.f;
        if (s < 256) {
          const float* q = xg0 + (size_t)s * 49152 + eb * 1536 + jg;
          gxr = q[0]; gxz = q[512]; gxn = q[1024];
        }
        if (wid < 6) {
          const u16* hs = hsrc + (rp << 14) + ((mt * 16 + (lane & 15)) << 9) + ((lane >> 4) * 8);
          f32x4 afr[16];
#pragma unroll
          for (int ks = 0; ks < 16; ++ks) afr[ks] = ld16cc(hs + ks * 32);
          asm volatile("s_waitcnt vmcnt(0)" ::: "memory");
          __builtin_amdgcn_sched_barrier(0);
          const int col = lane & 15, rb = (lane >> 4) << 2;
          if (s < 256) {
            f32x4 a0 = {0.f, 0.f, 0.f, 0.f}, a1 = {0.f, 0.f, 0.f, 0.f};
#pragma unroll
            for (int ks = 0; ks < 8; ++ks) {
              a0 = __builtin_amdgcn_mfma_f32_16x16x32_bf16(__builtin_bit_cast(bf16x8, afr[2 * ks]),     bfragH[2 * ks],     a0, 0, 0, 0);
              a1 = __builtin_amdgcn_mfma_f32_16x16x32_bf16(__builtin_bit_cast(bf16x8, afr[2 * ks + 1]), bfragH[2 * ks + 1], a1, 0, 0, 0);
            }
#pragma unroll
            for (int r = 0; r < 4; ++r) smD[mt][nt][rb + r][col] = a0[r] + a1[r];
          }
          if (s >= 1) {
            f32x4 c0 = {0.f, 0.f, 0.f, 0.f}, c1 = {0.f, 0.f, 0.f, 0.f};
#pragma unroll
            for (int ks = 0; ks < 8; ++ks) {
              c0 = __builtin_amdgcn_mfma_f32_16x16x32_bf16(__builtin_bit_cast(bf16x8, afr[2 * ks]),     bfragX[2 * ks],     c0, 0, 0, 0);
              c1 = __builtin_amdgcn_mfma_f32_16x16x32_bf16(__builtin_bit_cast(bf16x8, afr[2 * ks + 1]), bfragX[2 * ks + 1], c1, 0, 0, 0);
            }
            float* xp = x1x + wp * 49152;
#pragma unroll
            for (int r = 0; r < 4; ++r) {
              int ebr = mt * 16 + rb + r;
              __hip_atomic_store(xp + ((ebr * 3 + nt) << 9) + (blk << 4) + col,
                                 c0[r] + c1[r] + bX, __ATOMIC_RELAXED, __HIP_MEMORY_SCOPE_AGENT);
            }
          }
        }
        if (s < 256) {
          __syncthreads();
          float Dr = smD[eb >> 4][0][eb & 15][ejj] + bh_r;
          float Dz = smD[eb >> 4][1][eb & 15][ejj] + bh_z;
          float Dn = smD[eb >> 4][2][eb & 15][ejj] + bh_n;
          float r = sigm(gxr + Dr);
          float z = sigm(gxz + Dz);
          float n = tanhfast(gxn + r * Dn);
          h_own = (1.f - z) * n + z * h_own;
          unsigned hv = f2b(h_own);
          unsigned oth = __shfl_xor(hv, 1);
          if (!(ejj & 1))
            __hip_atomic_store((unsigned*)(hdst + (wp << 14)) + (((eb << 9) + jg) >> 1),
                               hv | (oth << 16), __ATOMIC_RELAXED, __HIP_MEMORY_SCOPE_AGENT);
        }
      }
    } else {  // role 1: layer-1 h update, t = s-2
      if (s >= 2) {
        float* xp = x1x + rp * 49152 + ((eb * 3) << 9) + jg;
        float gxr = __hip_atomic_load(xp,        __ATOMIC_RELAXED, __HIP_MEMORY_SCOPE_AGENT);
        float gxz = __hip_atomic_load(xp + 512,  __ATOMIC_RELAXED, __HIP_MEMORY_SCOPE_AGENT);
        float gxn = __hip_atomic_load(xp + 1024, __ATOMIC_RELAXED, __HIP_MEMORY_SCOPE_AGENT);
        if (wid < 6) {
          const u16* hs = hsrc + (rp << 14) + ((mt * 16 + (lane & 15)) << 9) + ((lane >> 4) * 8);
          f32x4 afr[16];
#pragma unroll
          for (int ks = 0; ks < 16; ++ks) afr[ks] = ld16cc(hs + ks * 32);
          asm volatile("s_waitcnt vmcnt(0)" ::: "memory");
          __builtin_amdgcn_sched_barrier(0);
          f32x4 a0 = {0.f, 0.f, 0.f, 0.f}, a1 = {0.f, 0.f, 0.f, 0.f};
#pragma unroll
          for (int ks = 0; ks < 8; ++ks) {
            a0 = __builtin_amdgcn_mfma_f32_16x16x32_bf16(__builtin_bit_cast(bf16x8, afr[2 * ks]),     bfragH[2 * ks],     a0, 0, 0, 0);
            a1 = __builtin_amdgcn_mfma_f32_16x16x32_bf16(__builtin_bit_cast(bf16x8, afr[2 * ks + 1]), bfragH[2 * ks + 1], a1, 0, 0, 0);
          }
          const int col = lane & 15, rb = (lane >> 4) << 2;
#pragma unroll
          for (int r = 0; r < 4; ++r) smD[mt][nt][rb + r][col] = a0[r] + a1[r];
        }
        __syncthreads();
        float Dr = smD[eb >> 4][0][eb & 15][ejj] + bh_r;
        float Dz = smD[eb >> 4][1][eb & 15][ejj] + bh_z;
        float Dn = smD[eb >> 4][2][eb & 15][ejj] + bh_n;
        float r = sigm(gxr + Dr);
        float z = sigm(gxz + Dz);
        float n = tanhfast(gxn + r * Dn);
        h_own = (1.f - z) * n + z * h_own;
        unsigned hv = f2b(h_own);
        unsigned oth = __shfl_xor(hv, 1);
        if (!(ejj & 1))
          __hip_atomic_store((unsigned*)(hdst + (wp << 14)) + (((eb << 9) + jg) >> 1),
                             hv | (oth << 16), __ATOMIC_RELAXED, __HIP_MEMORY_SCOPE_AGENT);
        h1seq[((size_t)((s - 2) * 32 + eb) << 9) + jg] = f2b(fmaxf(h_own, 0.f));
      }
    }
    // ---- fence-free grid barrier (no one consumes interval 257) ----
    if (s < 257) {
      asm volatile("s_waitcnt vmcnt(0)" ::: "memory");
      __syncthreads();
      if (tid == 0) {
        __hip_atomic_fetch_add(flags + ((s * 8 + (bid & 7)) << 4), 1,
                               __ATOMIC_RELAXED, __HIP_MEMORY_SCOPE_AGENT);
        int* fb = flags + ((s * 8) << 4);
        int sum;
        do {
          sum = 0;
#pragma unroll
          for (int i = 0; i < 8; ++i)
            sum += __hip_atomic_load(fb + (i << 4), __ATOMIC_RELAXED, __HIP_MEMORY_SCOPE_AGENT);
        } while (sum < NB);
      }
      __syncthreads();
    }
  }
}

// ---------------- in-place log_softmax over rows of 10000 ----------------
__global__ __launch_bounds__(256) void k_logsoftmax(float* __restrict__ out) {
  const int row = blockIdx.x, tid = threadIdx.x;
  float* p = out + (size_t)row * 10000;
  const int n_own = (tid < 16) ? 40 : 39;
  float v[40];
  float mx = -3.4e38f;
#pragma unroll
  for (int i = 0; i < 40; ++i)
    if (i < n_own) { v[i] = p[i * 256 + tid]; mx = fmaxf(mx, v[i]); }
  for (int o = 32; o; o >>= 1) mx = fmaxf(mx, __shfl_xor(mx, o));
  __shared__ float sm[4], ss[4];
  if ((tid & 63) == 0) sm[tid >> 6] = mx;
  __syncthreads();
  mx = fmaxf(fmaxf(sm[0], sm[1]), fmaxf(sm[2], sm[3]));
  float s = 0.f;
#pragma unroll
  for (int i = 0; i < 40; ++i)
    if (i < n_own) s += __expf(v[i] - mx);
  for (int o = 32; o; o >>= 1) s += __shfl_xor(s, o);
  if ((tid & 63) == 0) ss[tid >> 6] = s;
  __syncthreads();
  s = ss[0] + ss[1] + ss[2] + ss[3];
  float lse = mx + __logf(s);
#pragma unroll
  for (int i = 0; i < 40; ++i)
    if (i < n_own) p[i * 256 + tid] = v[i] - lse;
}

extern "C" void kernel_launch(void* const* d_in, const int* in_sizes, int n_in,
                              void* d_out, int out_size, void* d_ws, size_t ws_size,
                              hipStream_t stream) {
  (void)in_sizes; (void)n_in; (void)out_size;
  const int*   loc    = (const int*)  d_in[0];
  const float* times  = (const float*)d_in[1];
  const int*   labels = (const int*)  d_in[2];
  const float* emb    = (const float*)d_in[3];
  const float* traj   = (const float*)d_in[4];
  const float* w_ih0  = (const float*)d_in[5];
  const float* w_hh0  = (const float*)d_in[6];
  const float* b_ih0  = (const float*)d_in[7];
  const float* b_hh0  = (const float*)d_in[8];
  const float* w_ih1  = (const float*)d_in[9];
  const float* w_hh1  = (const float*)d_in[10];
  const float* b_ih1  = (const float*)d_in[11];
  const float* b_hh1  = (const float*)d_in[12];
  const float* fc_w   = (const float*)d_in[13];
  const float* fc_b   = (const float*)d_in[14];

  if (ws_size < 29800000) return;

  char* ws = (char*)d_ws;
  size_t off = 0;
  auto alloc = [&](size_t b) { size_t r = off; off += (b + 255) & ~(size_t)255; return r; };
  int*   flags = (int*)  (ws + alloc(258 * 8 * 16 * 4));
  u16*   h0x   = (u16*)  (ws + alloc(2 * 32 * 512 * 2));
  u16*   h1x   = (u16*)  (ws + alloc(2 * 32 * 512 * 2));
  float* x1x   = (float*)(ws + alloc(2 * 32 * 3 * 512 * 4));
  u16*   x0    = (u16*)  (ws + alloc((size_t)8192 * 288 * 2));
  u16*   wih0b = (u16*)  (ws + alloc((size_t)1536 * 288 * 2));
  u16*   whh0b = (u16*)  (ws + alloc((size_t)1536 * 512 * 2));
  u16*   wih1b = (u16*)  (ws + alloc((size_t)1536 * 512 * 2));
  u16*   whh1b = (u16*)  (ws + alloc((size_t)1536 * 512 * 2));
  u16*   fcwb  = (u16*)  (ws + alloc((size_t)10112 * 512 * 2));
  u16*   h1seq = (u16*)  (ws + alloc((size_t)8192 * 512 * 2));

  float* outp = (float*)d_out;
  float* xg0  = outp;                 // [8192][1536] scratch in d_out (dead until FC)
  float* tptr = outp + 81920000;      // time [8192]

  hipMemsetAsync(flags, 0, 258 * 8 * 16 * 4, stream);
  k_castpad<<<1024, 256, 0, stream>>>(w_ih0, wih0b, 1536, 257, 1536, 288);
  k_castpad<<<1024, 256, 0, stream>>>(w_hh0, whh0b, 1536, 512, 1536, 512);
  k_castpad<<<1024, 256, 0, stream>>>(w_ih1, wih1b, 1536, 512, 1536, 512);
  k_castpad<<<1024, 256, 0, stream>>>(w_hh1, whh1b, 1536, 512, 1536, 512);
  k_castpad<<<1024, 256, 0, stream>>>(fc_w, fcwb, 10001, 512, 10112, 512);
  k_embed<<<2048, 256, 0, stream>>>(loc, times, emb, x0);
  k_gemm<0><<<dim3(12, 64), 256, 0, stream>>>(x0, wih0b, b_ih0, xg0, 1536, 288, nullptr);
  k_hinit<<<64, 256, 0, stream>>>(traj, labels, h0x + 16384, 0);  // h0(-1) -> parity 1
  k_hinit<<<64, 256, 0, stream>>>(traj, labels, h1x + 16384, 1);  // h1(-1) -> parity 1
  k_scan2<<<NB, 512, 0, stream>>>(xg0, whh0b, b_hh0, wih1b, b_ih1, whh1b, b_hh1,
                                  traj, labels, h0x, h1x, x1x, h1seq, flags);
  k_gemm<1><<<dim3(79, 64), 256, 0, stream>>>(h1seq, fcwb, fc_b, outp, 10112, 512, tptr);
  k_logsoftmax<<<8192, 256, 0, stream>>>(outp);
}

// Round 3
// 1735.360 us; speedup vs baseline: 2.0901x; 1.0607x over previous
//
#include <hip/hip_runtime.h>

typedef unsigned short u16;
typedef __bf16 bf16x8 __attribute__((ext_vector_type(8)));
typedef float f32x4 __attribute__((ext_vector_type(4)));

#define DEVI __device__ __forceinline__

DEVI u16 f2b(float f) {
  union { float f; unsigned u; } c; c.f = f;
  unsigned r = c.u + 0x7FFFu + ((c.u >> 16) & 1u);
  return (u16)(r >> 16);
}

DEVI float sigm(float x) { return 1.f / (1.f + __expf(-x)); }
DEVI float tanhfast(float x) {
  x = fminf(fmaxf(x, -15.f), 15.f);
  float e = __expf(2.f * x);
  return (e - 1.f) / (e + 1.f);
}

DEVI void async16(const void* g, void* l) {
  __builtin_amdgcn_global_load_lds((const __attribute__((address_space(1))) void*)g,
                                   (__attribute__((address_space(3))) void*)l, 16, 0, 0);
}

// LLC-bypass 16B load (sc0 sc1). Caller must vmcnt(0)+sched_barrier before use.
DEVI f32x4 ld16cc(const u16* p) {
  f32x4 r;
  asm volatile("global_load_dwordx4 %0, %1, off sc0 sc1" : "=v"(r) : "v"(p) : "memory");
  return r;
}

// ---------------- cast / pad fp32 -> bf16 ----------------
__global__ __launch_bounds__(256) void k_castpad(const float* __restrict__ src, u16* __restrict__ dst,
                                                 int srows, int scols, int drows, int dcols) {
  size_t n = (size_t)drows * dcols;
  for (size_t i = blockIdx.x * 256 + threadIdx.x; i < n; i += (size_t)gridDim.x * 256) {
    int r = (int)(i / dcols), c = (int)(i % dcols);
    float v = (r < srows && c < scols) ? src[(size_t)r * scols + c] : 0.f;
    dst[i] = f2b(v);
  }
}

// ---------------- embedding + time concat -> x0 bf16 [8192][288] ----------------
__global__ __launch_bounds__(256) void k_embed(const int* __restrict__ loc, const float* __restrict__ times,
                                               const float* __restrict__ emb, u16* __restrict__ x0) {
  int m = blockIdx.x * 4 + (threadIdx.x >> 6);  // m = t*32 + b
  int s = threadIdx.x & 63;
  int b = m & 31, t = m >> 5;
  int li = loc[b * 256 + t];
  const float4* er = (const float4*)(emb + (size_t)li * 256);
  u16* xr = x0 + (size_t)m * 288;
  float4 v = er[s];
  ushort4 u;
  u.x = f2b(v.x); u.y = f2b(v.y); u.z = f2b(v.z); u.w = f2b(v.w);
  *(ushort4*)(xr + s * 4) = u;
  if (s == 0) xr[256] = f2b(times[b * 256 + t]);
  else if (s <= 31) xr[256 + s] = 0;
}

// ---------------- init h seed (bf16) from traj_emb[labels] ----------------
__global__ __launch_bounds__(256) void k_hinit(const float* __restrict__ traj, const int* __restrict__ labels,
                                               u16* __restrict__ dst, int layer) {
  int idx = blockIdx.x * 256 + threadIdx.x;
  if (idx < 16384) {
    int fidx = layer * 16384 + idx;
    dst[idx] = f2b(traj[(size_t)labels[fidx >> 10] * 1024 + (fidx & 1023)]);
  }
}

// ---------------- preset tag0[rep][0][w] = 1 ----------------
__global__ __launch_bounds__(128) void k_taginit(unsigned* __restrict__ tag0) {
  int t = threadIdx.x;           // t = rep*32 + w
  tag0[(t >> 5) * 259 * 32 + (t & 31)] = 1u;
}

// ---------------- bf16 MFMA GEMM: C[M,N] = A[M,K] * Bw[N,K]^T (+bias) ----------------
template <int MODE>
__global__ __launch_bounds__(256) void k_gemm(const u16* __restrict__ A, const u16* __restrict__ Bw,
                                              const float* __restrict__ bias, float* __restrict__ C,
                                              int N, int K, float* __restrict__ tptr) {
  __shared__ __align__(16) u16 As[128 * 32];
  __shared__ __align__(16) u16 Bs[128 * 32];
  const int tid = threadIdx.x;
  const int lane = tid & 63, wid = tid >> 6;
  const int tn = blockIdx.x, tm = blockIdx.y;
  const int wm = wid >> 1, wn = wid & 1;

  f32x4 acc[4][4] = {};

  const int r0 = tid >> 2;
  const int cb0 = (tid * 16) & 63;

  for (int k0 = 0; k0 < K; k0 += 32) {
    __syncthreads();
#pragma unroll
    for (int p = 0; p < 2; ++p) {
      int row = r0 + p * 64;
      const u16* ga = A + (size_t)(tm * 128 + row) * K + k0 + (cb0 >> 1);
      async16(ga, (void*)(As + wid * 512 + p * 2048));
      const u16* gb = Bw + (size_t)(tn * 128 + row) * K + k0 + (cb0 >> 1);
      async16(gb, (void*)(Bs + wid * 512 + p * 2048));
    }
    asm volatile("s_waitcnt vmcnt(0)" ::: "memory");
    __syncthreads();
    bf16x8 af[4], bf[4];
#pragma unroll
    for (int i = 0; i < 4; ++i) {
      af[i] = *reinterpret_cast<const bf16x8*>(As + (wm * 64 + i * 16 + (lane & 15)) * 32 + ((lane >> 4) * 8));
      bf[i] = *reinterpret_cast<const bf16x8*>(Bs + (wn * 64 + i * 16 + (lane & 15)) * 32 + ((lane >> 4) * 8));
    }
#pragma unroll
    for (int i = 0; i < 4; ++i)
#pragma unroll
      for (int j = 0; j < 4; ++j)
        acc[i][j] = __builtin_amdgcn_mfma_f32_16x16x32_bf16(af[i], bf[j], acc[i][j], 0, 0, 0);
  }

  const int row0 = tm * 128 + wm * 64;
  const int col0 = tn * 128 + wn * 64;
#pragma unroll
  for (int i = 0; i < 4; ++i)
#pragma unroll
    for (int j = 0; j < 4; ++j)
#pragma unroll
      for (int r = 0; r < 4; ++r) {
        int row = row0 + i * 16 + ((lane >> 4) * 4) + r;
        int col = col0 + j * 16 + (lane & 15);
        float v = acc[i][j][r];
        if (MODE == 0) {
          C[(size_t)row * N + col] = v + bias[col];
        } else {
          int orow = ((row & 31) << 8) + (row >> 5);  // b*256 + t
          if (col < 10000) C[(size_t)orow * 10000 + col] = v + bias[col];
          else if (col == 10000) tptr[orow] = sigm(v + bias[col]);
        }
      }
}

// ---------------- fused persistent 2-layer GRU scan, tag-flag sync ----------------
// 64 blocks x 512 thr, 1 block/CU (waves_per_eu(2,2) -> 256-VGPR budget, no spill).
// role0 (blk 0-31): h0 cols + X1 production (w_ih1 slice in LDS, XOR-swizzled).
// role1 (blk 32-63): h1 cols + h1seq.
// Sync: per-writer tag dwords tag[k][writer] (4 replicas). Reader lane polls one
// writer's flag, ballot over 64 lanes. h depth-2 is ack-free safe; x1x depth-8
// with slack-6 backpressure via tag1 folded into role0's ballot (lanes>=32).
__global__ __launch_bounds__(512) __attribute__((amdgpu_waves_per_eu(2, 2)))
void k_scan3(const float* __restrict__ xg0,
             const u16* __restrict__ whh0, const float* __restrict__ bhh0,
             const u16* __restrict__ wih1, const float* __restrict__ bih1,
             const u16* __restrict__ whh1, const float* __restrict__ bhh1,
             const float* __restrict__ traj, const int* __restrict__ labels,
             u16* __restrict__ h0x, u16* __restrict__ h1x, float* __restrict__ x1x,
             u16* __restrict__ h1seq, unsigned* __restrict__ tag0, unsigned* __restrict__ tag1)
{
  const int tid = threadIdx.x, bid = blockIdx.x;
  const int role = bid >> 5, blk = bid & 31;
  const int lane = tid & 63, wid = tid >> 6;
  const int rep = bid & 3;
  __shared__ float smD[2][3][16][16];
  __shared__ __align__(16) u16 xlds[24576];  // w_ih1 slice [48][512], XOR-swizzled

  const int eb = tid >> 4, ejj = tid & 15;
  const int jg = (blk << 4) + ejj;

  const float* bhh = (role == 0) ? bhh0 : bhh1;
  int fidx = (role == 1 ? 16384 : 0) + eb * 512 + jg;
  float h_own = traj[(size_t)labels[fidx >> 10] * 1024 + (fidx & 1023)];
  const float bh_r = bhh[jg], bh_z = bhh[512 + jg], bh_n = bhh[1024 + jg];

  const int mt = (wid < 6) ? wid / 3 : 0, nt = (wid < 6) ? wid % 3 : 0;
  bf16x8 bfragH[16];
  float bX = 0.f;
  if (wid < 6) {
    const u16* wh = (role == 0) ? whh0 : whh1;
    const u16* wrow = wh + (size_t)(nt * 512 + (blk << 4) + (lane & 15)) * 512 + ((lane >> 4) * 8);
#pragma unroll
    for (int ks = 0; ks < 16; ++ks)
      bfragH[ks] = *reinterpret_cast<const bf16x8*>(wrow + ks * 32);
    if (role == 0) bX = bih1[nt * 512 + (blk << 4) + (lane & 15)];
  }
  // preload w_ih1 slice into LDS (role0), XOR-swizzled rows
  if (role == 0) {
    for (int c = tid; c < 3072; c += 512) {  // 16B chunks of 48x1024B rows
      int row = c >> 6, o16 = c & 63;
      int grow = (row >> 4) * 512 + (blk << 4) + (row & 15);
      const float4* src = (const float4*)(wih1 + (size_t)grow * 512 + o16 * 8);
      int byte = (row << 10) + ((o16 * 16) ^ ((row & 7) << 4));
      *(float4*)((char*)xlds + byte) = *src;
    }
  }
  __syncthreads();

  const u16* hsrc = (role == 0) ? h0x : h1x;
  u16* hdst = (role == 0) ? h0x : h1x;
  unsigned* mytag = (role == 0) ? tag0 : tag1;

  for (int s = 0; s < 258; ++s) {
    if (role == 0 && s == 257) break;
    const int rp = (s + 1) & 1, wp = s & 1;

    if (role == 0) {
      // prefetch xg(s) — latency hides under tag wait
      float gxr = 0.f, gxz = 0.f, gxn = 0.f;
      if (s < 256) {
        const float* q = xg0 + (size_t)s * 49152 + eb * 1536 + jg;
        gxr = q[0]; gxz = q[512]; gxn = q[1024];
      }
      // poll: lanes<32 = h0(s-1) ready; lanes>=32 = x1x backpressure (slack 6)
      {
        const unsigned* tp;
        if (lane < 32)       tp = tag0 + ((size_t)(rep * 259 + s)) * 32 + lane;
        else if (s >= 9)     tp = tag1 + ((size_t)(rep * 259 + (s - 6))) * 32 + (lane - 32);
        else                 tp = tag0 + ((size_t)(rep * 259 + s)) * 32 + (lane - 32);
        while (__ballot(__hip_atomic_load(tp, __ATOMIC_RELAXED, __HIP_MEMORY_SCOPE_AGENT) != 0u) != ~0ull) {}
      }
      if (wid < 6) {
        const u16* hs = hsrc + (rp << 14) + ((mt * 16 + (lane & 15)) << 9) + ((lane >> 4) * 8);
        f32x4 afr[16];
#pragma unroll
        for (int ks = 0; ks < 16; ++ks) afr[ks] = ld16cc(hs + ks * 32);
        asm volatile("s_waitcnt vmcnt(0)" ::: "memory");
        __builtin_amdgcn_sched_barrier(0);
        const int col = lane & 15, rb = (lane >> 4) << 2;
        if (s < 256) {
          f32x4 a0 = {0.f, 0.f, 0.f, 0.f}, a1 = {0.f, 0.f, 0.f, 0.f};
#pragma unroll
          for (int ks = 0; ks < 8; ++ks) {
            a0 = __builtin_amdgcn_mfma_f32_16x16x32_bf16(__builtin_bit_cast(bf16x8, afr[2 * ks]),     bfragH[2 * ks],     a0, 0, 0, 0);
            a1 = __builtin_amdgcn_mfma_f32_16x16x32_bf16(__builtin_bit_cast(bf16x8, afr[2 * ks + 1]), bfragH[2 * ks + 1], a1, 0, 0, 0);
          }
#pragma unroll
          for (int r = 0; r < 4; ++r) smD[mt][nt][rb + r][col] = a0[r] + a1[r];
        }
        if (s >= 1) {
          const char* xbase = (const char*)xlds + ((nt * 16 + col) << 10);
          const int cb = (lane >> 4) << 4;
          const int swz = ((col & 7) << 4);  // (row&7)<<4 with row = nt*16+col
          f32x4 c0 = {0.f, 0.f, 0.f, 0.f}, c1 = {0.f, 0.f, 0.f, 0.f};
#pragma unroll
          for (int ks = 0; ks < 8; ++ks) {
            bf16x8 x0 = *(const bf16x8*)(xbase + (((2 * ks) * 64 + cb) ^ swz));
            bf16x8 x1 = *(const bf16x8*)(xbase + (((2 * ks + 1) * 64 + cb) ^ swz));
            c0 = __builtin_amdgcn_mfma_f32_16x16x32_bf16(__builtin_bit_cast(bf16x8, afr[2 * ks]),     x0, c0, 0, 0, 0);
            c1 = __builtin_amdgcn_mfma_f32_16x16x32_bf16(__builtin_bit_cast(bf16x8, afr[2 * ks + 1]), x1, c1, 0, 0, 0);
          }
          float* xp = x1x + (size_t)((s - 1) & 7) * 49152;
#pragma unroll
          for (int r = 0; r < 4; ++r) {
            int ebr = mt * 16 + rb + r;
            __hip_atomic_store(xp + ((ebr * 3 + nt) << 9) + (blk << 4) + col,
                               c0[r] + c1[r] + bX, __ATOMIC_RELAXED, __HIP_MEMORY_SCOPE_AGENT);
          }
        }
      }
      __syncthreads();
      if (s < 256) {
        float Dr = smD[eb >> 4][0][eb & 15][ejj] + bh_r;
        float Dz = smD[eb >> 4][1][eb & 15][ejj] + bh_z;
        float Dn = smD[eb >> 4][2][eb & 15][ejj] + bh_n;
        float r = sigm(gxr + Dr);
        float z = sigm(gxz + Dz);
        float n = tanhfast(gxn + r * Dn);
        h_own = (1.f - z) * n + z * h_own;
        unsigned hv = f2b(h_own);
        unsigned oth = __shfl_xor(hv, 1);
        if (!(ejj & 1))
          __hip_atomic_store((unsigned*)(hdst + (wp << 14)) + (((eb << 9) + jg) >> 1),
                             hv | (oth << 16), __ATOMIC_RELAXED, __HIP_MEMORY_SCOPE_AGENT);
      }
    } else {  // role 1: t = s-2
      if (s >= 2) {
        {
          const unsigned* tp = (lane < 32)
              ? tag0 + ((size_t)(rep * 259 + s)) * 32 + lane
              : tag1 + ((size_t)(rep * 259 + s)) * 32 + (lane - 32);
          while (__ballot(__hip_atomic_load(tp, __ATOMIC_RELAXED, __HIP_MEMORY_SCOPE_AGENT) != 0u) != ~0ull) {}
        }
        float* xp = x1x + (size_t)((s - 2) & 7) * 49152 + ((eb * 3) << 9) + jg;
        float gxr = __hip_atomic_load(xp,        __ATOMIC_RELAXED, __HIP_MEMORY_SCOPE_AGENT);
        float gxz = __hip_atomic_load(xp + 512,  __ATOMIC_RELAXED, __HIP_MEMORY_SCOPE_AGENT);
        float gxn = __hip_atomic_load(xp + 1024, __ATOMIC_RELAXED, __HIP_MEMORY_SCOPE_AGENT);
        if (wid < 6) {
          const u16* hs = hsrc + (rp << 14) + ((mt * 16 + (lane & 15)) << 9) + ((lane >> 4) * 8);
          f32x4 afr[16];
#pragma unroll
          for (int ks = 0; ks < 16; ++ks) afr[ks] = ld16cc(hs + ks * 32);
          asm volatile("s_waitcnt vmcnt(0)" ::: "memory");
          __builtin_amdgcn_sched_barrier(0);
          f32x4 a0 = {0.f, 0.f, 0.f, 0.f}, a1 = {0.f, 0.f, 0.f, 0.f};
#pragma unroll
          for (int ks = 0; ks < 8; ++ks) {
            a0 = __builtin_amdgcn_mfma_f32_16x16x32_bf16(__builtin_bit_cast(bf16x8, afr[2 * ks]),     bfragH[2 * ks],     a0, 0, 0, 0);
            a1 = __builtin_amdgcn_mfma_f32_16x16x32_bf16(__builtin_bit_cast(bf16x8, afr[2 * ks + 1]), bfragH[2 * ks + 1], a1, 0, 0, 0);
          }
          const int col = lane & 15, rb = (lane >> 4) << 2;
#pragma unroll
          for (int r = 0; r < 4; ++r) smD[mt][nt][rb + r][col] = a0[r] + a1[r];
        }
        __syncthreads();
        float Dr = smD[eb >> 4][0][eb & 15][ejj] + bh_r;
        float Dz = smD[eb >> 4][1][eb & 15][ejj] + bh_z;
        float Dn = smD[eb >> 4][2][eb & 15][ejj] + bh_n;
        float r = sigm(gxr + Dr);
        float z = sigm(gxz + Dz);
        float n = tanhfast(gxn + r * Dn);
        h_own = (1.f - z) * n + z * h_own;
        unsigned hv = f2b(h_own);
        unsigned oth = __shfl_xor(hv, 1);
        if (!(ejj & 1))
          __hip_atomic_store((unsigned*)(hdst + (wp << 14)) + (((eb << 9) + jg) >> 1),
                             hv | (oth << 16), __ATOMIC_RELAXED, __HIP_MEMORY_SCOPE_AGENT);
        h1seq[((size_t)((s - 2) * 32 + eb) << 9) + jg] = f2b(fmaxf(h_own, 0.f));
      }
    }
    // drain own publishes, then signal
    asm volatile("s_waitcnt vmcnt(0)" ::: "memory");
    __syncthreads();
    if (tid == 0 && s < 257) {
#pragma unroll
      for (int r = 0; r < 4; ++r)
        __hip_atomic_store(mytag + ((size_t)(r * 259 + s + 1)) * 32 + blk, 1u,
                           __ATOMIC_RELAXED, __HIP_MEMORY_SCOPE_AGENT);
    }
  }
}

// ---------------- in-place log_softmax over rows of 10000 ----------------
__global__ __launch_bounds__(256) void k_logsoftmax(float* __restrict__ out) {
  const int row = blockIdx.x, tid = threadIdx.x;
  float* p = out + (size_t)row * 10000;
  const int n_own = (tid < 16) ? 40 : 39;
  float v[40];
  float mx = -3.4e38f;
#pragma unroll
  for (int i = 0; i < 40; ++i)
    if (i < n_own) { v[i] = p[i * 256 + tid]; mx = fmaxf(mx, v[i]); }
  for (int o = 32; o; o >>= 1) mx = fmaxf(mx, __shfl_xor(mx, o));
  __shared__ float sm[4], ss[4];
  if ((tid & 63) == 0) sm[tid >> 6] = mx;
  __syncthreads();
  mx = fmaxf(fmaxf(sm[0], sm[1]), fmaxf(sm[2], sm[3]));
  float s = 0.f;
#pragma unroll
  for (int i = 0; i < 40; ++i)
    if (i < n_own) s += __expf(v[i] - mx);
  for (int o = 32; o; o >>= 1) s += __shfl_xor(s, o);
  if ((tid & 63) == 0) ss[tid >> 6] = s;
  __syncthreads();
  s = ss[0] + ss[1] + ss[2] + ss[3];
  float lse = mx + __logf(s);
#pragma unroll
  for (int i = 0; i < 40; ++i)
    if (i < n_own) p[i * 256 + tid] = v[i] - lse;
}

extern "C" void kernel_launch(void* const* d_in, const int* in_sizes, int n_in,
                              void* d_out, int out_size, void* d_ws, size_t ws_size,
                              hipStream_t stream) {
  (void)in_sizes; (void)n_in; (void)out_size;
  const int*   loc    = (const int*)  d_in[0];
  const float* times  = (const float*)d_in[1];
  const int*   labels = (const int*)  d_in[2];
  const float* emb    = (const float*)d_in[3];
  const float* traj   = (const float*)d_in[4];
  const float* w_ih0  = (const float*)d_in[5];
  const float* w_hh0  = (const float*)d_in[6];
  const float* b_ih0  = (const float*)d_in[7];
  const float* b_hh0  = (const float*)d_in[8];
  const float* w_ih1  = (const float*)d_in[9];
  const float* w_hh1  = (const float*)d_in[10];
  const float* b_ih1  = (const float*)d_in[11];
  const float* b_hh1  = (const float*)d_in[12];
  const float* fc_w   = (const float*)d_in[13];
  const float* fc_b   = (const float*)d_in[14];

  if (ws_size < 32000000) return;

  char* ws = (char*)d_ws;
  size_t off = 0;
  auto alloc = [&](size_t b) { size_t r = off; off += (b + 255) & ~(size_t)255; return r; };
  unsigned* tag0 = (unsigned*)(ws + alloc(4 * 259 * 32 * 4));   // 132608 B (mult of 256)
  unsigned* tag1 = (unsigned*)(ws + alloc(4 * 259 * 32 * 4));   // contiguous with tag0
  u16*   h0x   = (u16*)  (ws + alloc(2 * 32 * 512 * 2));
  u16*   h1x   = (u16*)  (ws + alloc(2 * 32 * 512 * 2));
  float* x1x   = (float*)(ws + alloc((size_t)8 * 32 * 3 * 512 * 4));
  u16*   x0    = (u16*)  (ws + alloc((size_t)8192 * 288 * 2));
  u16*   wih0b = (u16*)  (ws + alloc((size_t)1536 * 288 * 2));
  u16*   whh0b = (u16*)  (ws + alloc((size_t)1536 * 512 * 2));
  u16*   wih1b = (u16*)  (ws + alloc((size_t)1536 * 512 * 2));
  u16*   whh1b = (u16*)  (ws + alloc((size_t)1536 * 512 * 2));
  u16*   fcwb  = (u16*)  (ws + alloc((size_t)10112 * 512 * 2));
  u16*   h1seq = (u16*)  (ws + alloc((size_t)8192 * 512 * 2));

  float* outp = (float*)d_out;
  float* xg0  = outp;                 // [8192][1536] scratch in d_out (dead until FC)
  float* tptr = outp + 81920000;      // time [8192]

  hipMemsetAsync(tag0, 0, 2 * 4 * 259 * 32 * 4, stream);  // tag0+tag1 contiguous
  k_taginit<<<1, 128, 0, stream>>>(tag0);
  k_castpad<<<1024, 256, 0, stream>>>(w_ih0, wih0b, 1536, 257, 1536, 288);
  k_castpad<<<1024, 256, 0, stream>>>(w_hh0, whh0b, 1536, 512, 1536, 512);
  k_castpad<<<1024, 256, 0, stream>>>(w_ih1, wih1b, 1536, 512, 1536, 512);
  k_castpad<<<1024, 256, 0, stream>>>(w_hh1, whh1b, 1536, 512, 1536, 512);
  k_castpad<<<1024, 256, 0, stream>>>(fc_w, fcwb, 10001, 512, 10112, 512);
  k_embed<<<2048, 256, 0, stream>>>(loc, times, emb, x0);
  k_gemm<0><<<dim3(12, 64), 256, 0, stream>>>(x0, wih0b, b_ih0, xg0, 1536, 288, nullptr);
  k_hinit<<<64, 256, 0, stream>>>(traj, labels, h0x + 16384, 0);  // h0(-1) -> parity 1
  k_hinit<<<64, 256, 0, stream>>>(traj, labels, h1x + 16384, 1);  // h1(-1) -> parity 1
  k_scan3<<<64, 512, 0, stream>>>(xg0, whh0b, b_hh0, wih1b, b_ih1, whh1b, b_hh1,
                                  traj, labels, h0x, h1x, x1x, h1seq, tag0, tag1);
  k_gemm<1><<<dim3(79, 64), 256, 0, stream>>>(h1seq, fcwb, fc_b, outp, 10112, 512, tptr);
  k_logsoftmax<<<8192, 256, 0, stream>>>(outp);
}